// Round 1
// baseline (140551.294 us; speedup 1.0000x reference)
//
#include <hip/hip_runtime.h>

#define NTHR 512
#define NBLK 256

// problem dims
#define B_    256
#define TE_   300
#define T_    600
#define NIN_  128
#define H_    512
#define EMB_  32
#define KE0_  160
#define KD0_  133
#define OUT_HE_OFS 768000ull   // 256*600*5

// ---- workspace layout (float offsets) ----
constexpr size_t OF_BAR  = 0;                       // 64 floats (barrier counters)
constexpr size_t OF_XEMB = 64;                      // 256*32
constexpr size_t OF_HA   = OF_XEMB + 8192;          // 2 * 256*512
constexpr size_t OF_HB   = OF_HA + 262144;          // 2 * 256*512
constexpr size_t OF_PV   = OF_HB + 262144;          // 256*8
constexpr size_t OF_S1   = OF_PV + 2048;            // 256*128 relu(fc1)
constexpr size_t OF_S2   = OF_S1 + 32768;           // 256*128 relu(he1)
constexpr size_t OF_E0I  = OF_S2 + 32768;           // 32*160*48
constexpr size_t OF_E0H  = OF_E0I + 245760;         // 32*512*48
constexpr size_t OF_E1I  = OF_E0H + 786432;
constexpr size_t OF_E1H  = OF_E1I + 786432;
constexpr size_t OF_D0I  = OF_E1H + 786432;         // 32*133*48
constexpr size_t OF_D0H  = OF_D0I + 204288;
constexpr size_t OF_D1I  = OF_D0H + 786432;
constexpr size_t OF_D1H  = OF_D1I + 786432;
constexpr size_t OF_FH   = OF_D1H + 786432;         // 32*512*8 (fc1+he1 cols)
constexpr size_t WS_END  = OF_FH + 131072;          // ~23.6 MB total

// ---------------- init: zero barrier, build xemb, pv state, zero h slot-1 ----------------
__global__ void k_init(float* __restrict__ ws, const float* __restrict__ pv_init,
                       const int* __restrict__ scen, const float* __restrict__ emb) {
  const size_t total = 64 + 8192 + 2048 + 131072 + 131072;
  size_t stride = (size_t)gridDim.x * blockDim.x;
  for (size_t x = (size_t)blockIdx.x * blockDim.x + threadIdx.x; x < total; x += stride) {
    if (x < 64) {
      ((unsigned*)ws)[x] = 0u;
    } else if (x < 64 + 8192) {
      size_t r = x - 64; int b = (int)(r >> 5), e = (int)(r & 31);
      ws[OF_XEMB + r] = emb[scen[b] * EMB_ + e];
    } else if (x < 64 + 8192 + 2048) {
      size_t r = x - 64 - 8192; int b = (int)(r >> 3), p = (int)(r & 7);
      ws[OF_PV + r] = (p < 5) ? pv_init[b * 5 + p] : 0.f;
    } else if (x < 64 + 8192 + 2048 + 131072) {
      ws[OF_HA + 131072 + (x - 64 - 8192 - 2048)] = 0.f;        // hA slot 1 = zeros
    } else {
      ws[OF_HB + 131072 + (x - 64 - 8192 - 2048 - 131072)] = 0.f; // hB slot 1 = zeros
    }
  }
}

// ---------------- weight rearrange: dst[g][k][c], c = gate*16 + hid_local ----------------
__global__ void k_rearr(float* __restrict__ dst, const float* __restrict__ src, int K) {
  int n = 32 * 48 * K;
  for (int idx = blockIdx.x * blockDim.x + threadIdx.x; idx < n; idx += gridDim.x * blockDim.x) {
    int g = idx / (K * 48), r = idx % (K * 48), k = r / 48, c = r % 48;
    int j = (c >> 4) * 512 + g * 16 + (c & 15);
    dst[idx] = src[j * K + k];
  }
}
// fc1/he1 combined: dst[g][k][c] (c<4: fc1 col g*4+c; c>=4: he1 col g*4+c-4), K=512
__global__ void k_rearr_fh(float* __restrict__ dst, const float* __restrict__ fc1,
                           const float* __restrict__ he1) {
  int n = 32 * 512 * 8;
  for (int idx = blockIdx.x * blockDim.x + threadIdx.x; idx < n; idx += gridDim.x * blockDim.x) {
    int g = idx / (512 * 8), r = idx % (512 * 8), k = r / 8, c = r % 8;
    const float* s = (c < 4) ? fc1 : he1;
    dst[idx] = s[(g * 4 + (c & 3)) * 512 + k];
  }
}

// ---------------- device helpers ----------------
__device__ __forceinline__ float sigm(float x) { return 1.f / (1.f + __expf(-x)); }
__device__ __forceinline__ float tanhx(float x) { float e = __expf(2.f * x); return 1.f - 2.f / (e + 1.f); }

// sense-reversing device-scope grid barrier (all NBLK blocks are co-resident: 1 block/CU)
__device__ __forceinline__ void bar_sync(unsigned* bar) {
  __syncthreads();
  if (threadIdx.x == 0) {
    unsigned gen = __hip_atomic_load(&bar[1], __ATOMIC_RELAXED, __HIP_MEMORY_SCOPE_AGENT);
    unsigned n = __hip_atomic_fetch_add(&bar[0], 1u, __ATOMIC_ACQ_REL, __HIP_MEMORY_SCOPE_AGENT);
    if (n == NBLK - 1) {
      __hip_atomic_store(&bar[0], 0u, __ATOMIC_RELAXED, __HIP_MEMORY_SCOPE_AGENT);
      __hip_atomic_store(&bar[1], gen + 1u, __ATOMIC_RELEASE, __HIP_MEMORY_SCOPE_AGENT);
    } else {
      while (__hip_atomic_load(&bar[1], __ATOMIC_ACQUIRE, __HIP_MEMORY_SCOPE_AGENT) == gen)
        __builtin_amdgcn_s_sleep(2);
    }
  }
  __syncthreads();
}

// stage one 64-k tile of a [B,512] row-major matrix into s_act[k][33] (transposed, padded)
__device__ __forceinline__ void stage_h(const float* __restrict__ src, int b0, int k0,
                                        float* __restrict__ s_act) {
  int row = threadIdx.x >> 4, ko = (threadIdx.x & 15) << 2;
  float4 v = *(const float4*)(src + (size_t)(b0 + row) * H_ + k0 + ko);
  s_act[(ko + 0) * 33 + row] = v.x; s_act[(ko + 1) * 33 + row] = v.y;
  s_act[(ko + 2) * 33 + row] = v.z; s_act[(ko + 3) * 33 + row] = v.w;
}

#define GRU_FMA(ACC3)                                            \
  {                                                              \
    float a = s_act[k * 33 + bl];                                \
    aR = fmaf(a, s_w[k * 48 + hc], aR);                          \
    aZ = fmaf(a, s_w[k * 48 + 16 + hc], aZ);                     \
    ACC3 = fmaf(a, s_w[k * 48 + 32 + hc], ACC3);                 \
  }

// One GRU step for this WG's tile: 32 batch rows (b0..b0+31) x 16 hidden (g*16..+15).
// KIND 0: enc L0 (act = x_cv[t] ++ xemb), 1: plain H matrix, 2: dec L0 (x_tgt[t] ++ pv in s_pvl)
template <int KIND, int KI>
__device__ void gru_tile(const float* __restrict__ actA, const float* __restrict__ actB, int t,
                         const float* __restrict__ wi, const float* __restrict__ wh,
                         const float* __restrict__ bi, const float* __restrict__ bh,
                         const float* __restrict__ hprev, float* __restrict__ hout,
                         int b0, int g, float* __restrict__ s_act, float* __restrict__ s_w,
                         const float* __restrict__ s_pvl) {
  const int tid = threadIdx.x;
  const int bl = tid & 31;
  const int hc = tid >> 5;            // 0..15
  const int hid = (g << 4) + hc;
  float aR = 0.f, aZ = 0.f, aI = 0.f, aN = 0.f;

  // ---- input dot (K = KI) ----
  constexpr int NT = (KI + 63) >> 6;
  for (int kt = 0; kt < NT; ++kt) {
    const int k0 = kt << 6;
    const int cnt = (KI - k0 >= 64) ? 64 : (KI - k0);
    __syncthreads();
    // act staging
    if (KIND == 1) {
      stage_h(actA, b0, k0, s_act);
    } else if (KIND == 0) {
      int row = tid >> 4, ko = (tid & 15) << 2;
      if (k0 < 128) {
        float4 v = *(const float4*)(actA + ((size_t)(b0 + row) * TE_ + t) * NIN_ + k0 + ko);
        s_act[(ko + 0) * 33 + row] = v.x; s_act[(ko + 1) * 33 + row] = v.y;
        s_act[(ko + 2) * 33 + row] = v.z; s_act[(ko + 3) * 33 + row] = v.w;
      } else if (ko < 32) {
        float4 v = *(const float4*)(actB + (size_t)(b0 + row) * EMB_ + ko);
        s_act[(ko + 0) * 33 + row] = v.x; s_act[(ko + 1) * 33 + row] = v.y;
        s_act[(ko + 2) * 33 + row] = v.z; s_act[(ko + 3) * 33 + row] = v.w;
      }
    } else { // DEC0
      int row = tid >> 4, ko = (tid & 15) << 2;
      if (k0 < 128) {
        float4 v = *(const float4*)(actA + ((size_t)(b0 + row) * T_ + t) * NIN_ + k0 + ko);
        s_act[(ko + 0) * 33 + row] = v.x; s_act[(ko + 1) * 33 + row] = v.y;
        s_act[(ko + 2) * 33 + row] = v.z; s_act[(ko + 3) * 33 + row] = v.w;
      } else if ((tid & 15) == 0) {
#pragma unroll
        for (int i2 = 0; i2 < 5; ++i2) s_act[i2 * 33 + row] = s_pvl[(row << 3) + i2];
      }
    }
    // weight staging: flat contiguous [cnt][48]
    {
      const int n4 = cnt * 12;
      const float4* s4 = (const float4*)(wi + ((size_t)g * KI + k0) * 48);
      float4* d4 = (float4*)s_w;
      for (int i2 = tid; i2 < n4; i2 += NTHR) d4[i2] = s4[i2];
    }
    __syncthreads();
    if (cnt == 64) {
#pragma unroll 8
      for (int k = 0; k < 64; ++k) GRU_FMA(aI)
    } else {
      for (int k = 0; k < cnt; ++k) GRU_FMA(aI)
    }
  }

  // ---- hidden dot (K = 512) ----
  for (int kt = 0; kt < 8; ++kt) {
    const int k0 = kt << 6;
    __syncthreads();
    stage_h(hprev, b0, k0, s_act);
    {
      const float4* s4 = (const float4*)(wh + ((size_t)(g << 9) + k0) * 48);
      float4* d4 = (float4*)s_w;
      for (int i2 = tid; i2 < 768; i2 += NTHR) d4[i2] = s4[i2];
    }
    __syncthreads();
#pragma unroll 8
    for (int k = 0; k < 64; ++k) GRU_FMA(aN)
  }

  // epilogue (PyTorch GRU: r,z,n gate order)
  float r = sigm(aR + bi[hid] + bh[hid]);
  float z = sigm(aZ + bi[512 + hid] + bh[512 + hid]);
  float n = tanhx(aI + bi[1024 + hid] + r * (aN + bh[1024 + hid]));
  float hp = hprev[(size_t)(b0 + bl) * H_ + hid];
  hout[(size_t)(b0 + bl) * H_ + hid] = (1.f - z) * n + z * hp;
}

// ---------------- the persistent kernel ----------------
__global__ __launch_bounds__(NTHR) void k_main(
    float* __restrict__ ws, const float* __restrict__ x_cv, const float* __restrict__ x_tgt,
    const float* __restrict__ e_bi0, const float* __restrict__ e_bh0,
    const float* __restrict__ e_bi1, const float* __restrict__ e_bh1,
    const float* __restrict__ d_bi0, const float* __restrict__ d_bh0,
    const float* __restrict__ d_bi1, const float* __restrict__ d_bh1,
    const float* __restrict__ fc1_b, const float* __restrict__ fc2_W, const float* __restrict__ fc2_b,
    const float* __restrict__ he1_b, const float* __restrict__ he2_W, const float* __restrict__ he2_b,
    float* __restrict__ out) {
  __shared__ float s_act[64 * 33];
  __shared__ float s_w[64 * 48];
  __shared__ float s_pv[256];        // [32 rows][8] pv values for this b-group
  __shared__ float s_sb[32 * 132];   // staging for s1/s2 rows

  const int tid = threadIdx.x;
  const int wg = blockIdx.x;
  const int bi = wg & 7;             // b-group -> XCD-local via round-robin heuristic
  const int ji = wg >> 3;            // 0..31 hidden group
  const int b0 = bi << 5;            // 32 rows per group

  unsigned* bar = (unsigned*)ws;
  float* xemb = ws + OF_XEMB;
  float* hA[2] = {ws + OF_HA, ws + OF_HA + 131072};
  float* hB[2] = {ws + OF_HB, ws + OF_HB + 131072};
  float* pvst = ws + OF_PV;
  float* s1g = ws + OF_S1;
  float* s2g = ws + OF_S2;
  const float* wE0I = ws + OF_E0I; const float* wE0H = ws + OF_E0H;
  const float* wE1I = ws + OF_E1I; const float* wE1H = ws + OF_E1H;
  const float* wD0I = ws + OF_D0I; const float* wD0H = ws + OF_D0H;
  const float* wD1I = ws + OF_D1I; const float* wD1H = ws + OF_D1H;
  const float* wFH  = ws + OF_FH;

  // ======== encoder: L0 and L1 pipelined (L1 lags one step) ========
  for (int s = 0; s <= TE_; ++s) {
    if (s < TE_)
      gru_tile<0, KE0_>(x_cv, xemb, s, wE0I, wE0H, e_bi0, e_bh0,
                        hA[(s + 1) & 1], hA[s & 1], b0, ji, s_act, s_w, nullptr);
    if (s >= 1)
      gru_tile<1, 512>(hA[(s + 1) & 1], nullptr, 0, wE1I, wE1H, e_bi1, e_bh1,
                       hB[s & 1], hB[(s + 1) & 1], b0, ji, s_act, s_w, nullptr);
    bar_sync(bar);
  }
  // h1_fin in hA[1], h2_fin in hB[1]

  // ======== decoder ========
  for (int t = 0; t <= T_; ++t) {
    // ---- heads of step t-1 (pv feedback + outputs), or pv_init at t==0 ----
    if (t == 0) {
      if (tid < 256) s_pv[tid] = pvst[(b0 << 3) + tid];
      __syncthreads();
    } else {
      { // stage s1 rows for this b-group
        int row = tid >> 4, co = (tid & 15) << 3;
        float4 v0 = *(const float4*)(s1g + (size_t)(b0 + row) * 128 + co);
        float4 v1 = *(const float4*)(s1g + (size_t)(b0 + row) * 128 + co + 4);
        *(float4*)(s_sb + row * 132 + co) = v0;
        *(float4*)(s_sb + row * 132 + co + 4) = v1;
      }
      __syncthreads();
      if (tid < 160) { // pv = s1 @ fc2^T + b  (redundant per WG; needed for pv feedback)
        int bl2 = tid & 31, p = tid >> 5;
        float acc = fc2_b[p];
#pragma unroll 8
        for (int c = 0; c < 128; ++c) acc = fmaf(s_sb[bl2 * 132 + c], fc2_W[p * 128 + c], acc);
        s_pv[(bl2 << 3) + p] = acc;
      }
      __syncthreads();
      if (ji == 1 && tid < 160) { // one WG per b-group writes pv output
        int bl2 = tid & 31, p = tid >> 5;
        out[((size_t)(b0 + bl2) * T_ + (t - 1)) * 5 + p] = s_pv[(bl2 << 3) + p];
      }
      if (ji == 0) { // one WG per b-group computes + writes he output
        int row = tid >> 4, co = (tid & 15) << 3;
        float4 v0 = *(const float4*)(s2g + (size_t)(b0 + row) * 128 + co);
        float4 v1 = *(const float4*)(s2g + (size_t)(b0 + row) * 128 + co + 4);
        *(float4*)(s_sb + row * 132 + co) = v0;
        *(float4*)(s_sb + row * 132 + co + 4) = v1;
        __syncthreads();
        int bl2 = tid & 31, e = tid >> 5;
        float acc = he2_b[e];
#pragma unroll 8
        for (int c = 0; c < 128; ++c) acc = fmaf(s_sb[bl2 * 132 + c], he2_W[e * 128 + c], acc);
        out[OUT_HE_OFS + ((size_t)(b0 + bl2) * T_ + (t - 1)) * 16 + e] = acc;
      }
    }

    if (t < T_) {
      // ---- phase D0: d1_t ----
      gru_tile<2, KD0_>(x_tgt, nullptr, t, wD0I, wD0H, d_bi0, d_bh0,
                        hA[(t + 1) & 1], hA[t & 1], b0, ji, s_act, s_w, s_pv);
      bar_sync(bar);
      // ---- phase D1: d2_t ----
      gru_tile<1, 512>(hA[t & 1], nullptr, 0, wD1I, wD1H, d_bi1, d_bh1,
                       hB[(t + 1) & 1], hB[t & 1], b0, ji, s_act, s_w, nullptr);
      bar_sync(bar);
      // ---- phase H1: s1 = relu(d2@fc1^T + b), s2 = relu(d2@he1^T + b) ----
      {
        const float* d2 = hB[t & 1];
        int bl2 = tid & 31, c = tid >> 5; // c 0..15, active c<8
        float acc = 0.f;
        for (int kt = 0; kt < 8; ++kt) {
          int k0 = kt << 6;
          __syncthreads();
          stage_h(d2, b0, k0, s_act);
          {
            const float4* s4 = (const float4*)(wFH + ((size_t)(ji << 9) + k0) * 8);
            float4* d4 = (float4*)s_w;
            for (int i2 = tid; i2 < 128; i2 += NTHR) d4[i2] = s4[i2];
          }
          __syncthreads();
          if (c < 8) {
#pragma unroll 8
            for (int k = 0; k < 64; ++k) acc = fmaf(s_act[k * 33 + bl2], s_w[(k << 3) + c], acc);
          }
        }
        if (c < 4)
          s1g[(size_t)(b0 + bl2) * 128 + (ji << 2) + c] = fmaxf(acc + fc1_b[(ji << 2) + c], 0.f);
        else if (c < 8)
          s2g[(size_t)(b0 + bl2) * 128 + (ji << 2) + c - 4] = fmaxf(acc + he1_b[(ji << 2) + c - 4], 0.f);
      }
      bar_sync(bar);
    }
  }
}

// ---------------- host ----------------
extern "C" void kernel_launch(void* const* d_in, const int* in_sizes, int n_in,
                              void* d_out, int out_size, void* d_ws, size_t ws_size,
                              hipStream_t stream) {
  float* ws = (float*)d_ws;
  const float* x_cv   = (const float*)d_in[0];
  const float* x_tgt  = (const float*)d_in[1];
  const float* pv_init= (const float*)d_in[2];
  const int*   scen   = (const int*)d_in[3];
  const float* emb    = (const float*)d_in[4];
  const float* eWih0  = (const float*)d_in[5];
  const float* eWhh0  = (const float*)d_in[6];
  const float* ebi0   = (const float*)d_in[7];
  const float* ebh0   = (const float*)d_in[8];
  const float* eWih1  = (const float*)d_in[9];
  const float* eWhh1  = (const float*)d_in[10];
  const float* ebi1   = (const float*)d_in[11];
  const float* ebh1   = (const float*)d_in[12];
  const float* dWih0  = (const float*)d_in[13];
  const float* dWhh0  = (const float*)d_in[14];
  const float* dbi0   = (const float*)d_in[15];
  const float* dbh0   = (const float*)d_in[16];
  const float* dWih1  = (const float*)d_in[17];
  const float* dWhh1  = (const float*)d_in[18];
  const float* dbi1   = (const float*)d_in[19];
  const float* dbh1   = (const float*)d_in[20];
  const float* fc1W   = (const float*)d_in[21];
  const float* fc1b   = (const float*)d_in[22];
  const float* fc2W   = (const float*)d_in[23];
  const float* fc2b   = (const float*)d_in[24];
  const float* he1W   = (const float*)d_in[25];
  const float* he1b   = (const float*)d_in[26];
  const float* he2W   = (const float*)d_in[27];
  const float* he2b   = (const float*)d_in[28];

  hipLaunchKernelGGL(k_init, dim3(512), dim3(256), 0, stream, ws, pv_init, scen, emb);
  hipLaunchKernelGGL(k_rearr, dim3(512), dim3(256), 0, stream, ws + OF_E0I, eWih0, 160);
  hipLaunchKernelGGL(k_rearr, dim3(512), dim3(256), 0, stream, ws + OF_E0H, eWhh0, 512);
  hipLaunchKernelGGL(k_rearr, dim3(512), dim3(256), 0, stream, ws + OF_E1I, eWih1, 512);
  hipLaunchKernelGGL(k_rearr, dim3(512), dim3(256), 0, stream, ws + OF_E1H, eWhh1, 512);
  hipLaunchKernelGGL(k_rearr, dim3(512), dim3(256), 0, stream, ws + OF_D0I, dWih0, 133);
  hipLaunchKernelGGL(k_rearr, dim3(512), dim3(256), 0, stream, ws + OF_D0H, dWhh0, 512);
  hipLaunchKernelGGL(k_rearr, dim3(512), dim3(256), 0, stream, ws + OF_D1I, dWih1, 512);
  hipLaunchKernelGGL(k_rearr, dim3(512), dim3(256), 0, stream, ws + OF_D1H, dWhh1, 512);
  hipLaunchKernelGGL(k_rearr_fh, dim3(256), dim3(256), 0, stream, ws + OF_FH, fc1W, he1W);

  hipLaunchKernelGGL(k_main, dim3(NBLK), dim3(NTHR), 0, stream,
                     ws, x_cv, x_tgt, ebi0, ebh0, ebi1, ebh1, dbi0, dbh0, dbi1, dbh1,
                     fc1b, fc2W, fc2b, he1b, he2W, he2b, (float*)d_out);
}

// Round 2
// 124190.930 us; speedup vs baseline: 1.1317x; 1.1317x over previous
//
#include <hip/hip_runtime.h>

#define NTHR 512
#define NBLK 256

// problem dims
#define B_    256
#define TE_   300
#define T_    600
#define NIN_  128
#define H_    512
#define EMB_  32
#define KE0_  160
#define KD0_  133
#define OUT_HE_OFS 768000ull   // 256*600*5

// ---- workspace layout (float offsets) ----
constexpr size_t OF_BAR  = 0;                       // 1024 floats (tree barrier)
constexpr size_t OF_XEMB = 1024;                    // 256*32
constexpr size_t OF_HA   = OF_XEMB + 8192;          // 2 * 256*512
constexpr size_t OF_HB   = OF_HA + 262144;          // 2 * 256*512
constexpr size_t OF_PV   = OF_HB + 262144;          // 256*8
constexpr size_t OF_S1   = OF_PV + 2048;            // 256*128 relu(fc1)
constexpr size_t OF_S2   = OF_S1 + 32768;           // 256*128 relu(he1)
constexpr size_t OF_E0I  = OF_S2 + 32768;           // 32*160*48
constexpr size_t OF_E0H  = OF_E0I + 245760;         // 32*512*48
constexpr size_t OF_E1I  = OF_E0H + 786432;
constexpr size_t OF_E1H  = OF_E1I + 786432;
constexpr size_t OF_D0I  = OF_E1H + 786432;         // 32*133*48
constexpr size_t OF_D0H  = OF_D0I + 204288;
constexpr size_t OF_D1I  = OF_D0H + 786432;
constexpr size_t OF_D1H  = OF_D1I + 786432;
constexpr size_t OF_FH   = OF_D1H + 786432;         // 32*512*8 (fc1+he1 cols)
constexpr size_t WS_END  = OF_FH + 131072;          // ~23.6 MB total

// ---------------- init: zero barrier, build xemb, pv state, zero h slot-1 ----------------
__global__ void k_init(float* __restrict__ ws, const float* __restrict__ pv_init,
                       const int* __restrict__ scen, const float* __restrict__ emb) {
  const size_t total = 1024 + 8192 + 2048 + 131072 + 131072;
  size_t stride = (size_t)gridDim.x * blockDim.x;
  for (size_t x = (size_t)blockIdx.x * blockDim.x + threadIdx.x; x < total; x += stride) {
    if (x < 1024) {
      ((unsigned*)ws)[x] = 0u;
    } else if (x < 1024 + 8192) {
      size_t r = x - 1024; int b = (int)(r >> 5), e = (int)(r & 31);
      ws[OF_XEMB + r] = emb[scen[b] * EMB_ + e];
    } else if (x < 1024 + 8192 + 2048) {
      size_t r = x - 1024 - 8192; int b = (int)(r >> 3), p = (int)(r & 7);
      ws[OF_PV + r] = (p < 5) ? pv_init[b * 5 + p] : 0.f;
    } else if (x < 1024 + 8192 + 2048 + 131072) {
      ws[OF_HA + 131072 + (x - 1024 - 8192 - 2048)] = 0.f;        // hA slot 1 = zeros
    } else {
      ws[OF_HB + 131072 + (x - 1024 - 8192 - 2048 - 131072)] = 0.f; // hB slot 1 = zeros
    }
  }
}

// ---------------- weight rearrange: dst[g][k][c], c = gate*16 + hid_local ----------------
__global__ void k_rearr(float* __restrict__ dst, const float* __restrict__ src, int K) {
  int n = 32 * 48 * K;
  for (int idx = blockIdx.x * blockDim.x + threadIdx.x; idx < n; idx += gridDim.x * blockDim.x) {
    int g = idx / (K * 48), r = idx % (K * 48), k = r / 48, c = r % 48;
    int j = (c >> 4) * 512 + g * 16 + (c & 15);
    dst[idx] = src[j * K + k];
  }
}
// fc1/he1 combined: dst[g][k][c] (c<4: fc1 col g*4+c; c>=4: he1 col g*4+c-4), K=512
__global__ void k_rearr_fh(float* __restrict__ dst, const float* __restrict__ fc1,
                           const float* __restrict__ he1) {
  int n = 32 * 512 * 8;
  for (int idx = blockIdx.x * blockDim.x + threadIdx.x; idx < n; idx += gridDim.x * blockDim.x) {
    int g = idx / (512 * 8), r = idx % (512 * 8), k = r / 8, c = r % 8;
    const float* s = (c < 4) ? fc1 : he1;
    dst[idx] = s[(g * 4 + (c & 3)) * 512 + k];
  }
}

// ---------------- device helpers ----------------
__device__ __forceinline__ float sigm(float x) { return 1.f / (1.f + __expf(-x)); }
__device__ __forceinline__ float tanhx(float x) { float e = __expf(2.f * x); return 1.f - 2.f / (e + 1.f); }

// two-level sense-reversing grid barrier: 16 groups of 16 WGs (64B-spread counters) + root
// counters: bar[g*32] g<16; root: bar[512]; generation: bar[520]
__device__ __forceinline__ void bar_sync(unsigned* bar, int wg) {
  __syncthreads();
  if (threadIdx.x == 0) {
    unsigned gen = __hip_atomic_load(&bar[520], __ATOMIC_RELAXED, __HIP_MEMORY_SCOPE_AGENT);
    unsigned n = __hip_atomic_fetch_add(&bar[(wg >> 4) << 5], 1u, __ATOMIC_ACQ_REL, __HIP_MEMORY_SCOPE_AGENT);
    if (n == 15u) {
      unsigned r = __hip_atomic_fetch_add(&bar[512], 1u, __ATOMIC_ACQ_REL, __HIP_MEMORY_SCOPE_AGENT);
      if (r == 15u) {
        __hip_atomic_store(&bar[512], 0u, __ATOMIC_RELAXED, __HIP_MEMORY_SCOPE_AGENT);
#pragma unroll
        for (int i = 0; i < 16; ++i)
          __hip_atomic_store(&bar[i << 5], 0u, __ATOMIC_RELAXED, __HIP_MEMORY_SCOPE_AGENT);
        __hip_atomic_store(&bar[520], gen + 1u, __ATOMIC_RELEASE, __HIP_MEMORY_SCOPE_AGENT);
      }
    }
    while (__hip_atomic_load(&bar[520], __ATOMIC_ACQUIRE, __HIP_MEMORY_SCOPE_AGENT) == gen)
      __builtin_amdgcn_s_sleep(1);
  }
  __syncthreads();
}

#define GRU_FMA(ACC3)                                            \
  {                                                              \
    float a = s_act[k * 33 + bl];                                \
    aR = fmaf(a, s_w[k * 48 + hc], aR);                          \
    aZ = fmaf(a, s_w[k * 48 + 16 + hc], aZ);                     \
    ACC3 = fmaf(a, s_w[k * 48 + 32 + hc], ACC3);                 \
  }

// register prefetch of one 64-k tile's operands (global -> VGPR)
template <int KIND, int KI>
__device__ __forceinline__ void load_tile_regs(
    int kt, int tid, int b0, int g, int t, int row, int ko,
    const float* __restrict__ actA, const float* __restrict__ actB,
    const float* __restrict__ wi, const float* __restrict__ wh,
    const float* __restrict__ hprev,
    float4& wv0, float4& wv1, float4& av, int& n4, bool& a_valid) {
  constexpr int NTI = (KI + 63) >> 6;
  if (kt < NTI) {
    const int k0 = kt << 6;
    const int cnt = (KI - k0 >= 64) ? 64 : (KI - k0);
    n4 = cnt * 12;
    const float4* s4 = (const float4*)(wi + ((size_t)g * KI + k0) * 48);
    if (tid < n4) wv0 = s4[tid];
    if (tid + 512 < n4) wv1 = s4[tid + 512];
    a_valid = false;
    if (KIND == 1) {
      av = *(const float4*)(actA + (size_t)(b0 + row) * H_ + k0 + ko);
      a_valid = true;
    } else if (KIND == 0) {
      if (k0 < 128) {
        av = *(const float4*)(actA + ((size_t)(b0 + row) * TE_ + t) * NIN_ + k0 + ko);
        a_valid = true;
      } else if (ko < 32) {
        av = *(const float4*)(actB + (size_t)(b0 + row) * EMB_ + ko);
        a_valid = true;
      }
    } else { // DEC L0
      if (k0 < 128) {
        av = *(const float4*)(actA + ((size_t)(b0 + row) * T_ + t) * NIN_ + k0 + ko);
        a_valid = true;
      } // pv tail handled at store time from LDS
    }
  } else {
    const int k0 = (kt - NTI) << 6;
    n4 = 768;
    const float4* s4 = (const float4*)(wh + ((size_t)(g << 9) + k0) * 48);
    wv0 = s4[tid];
    if (tid < 256) wv1 = s4[tid + 512];
    av = *(const float4*)(hprev + (size_t)(b0 + row) * H_ + k0 + ko);
    a_valid = true;
  }
}

// One GRU step for this WG's tile: 32 batch rows x 16 hidden cols; double-buffered staging.
// KIND 0: enc L0 (x_cv ++ xemb), 1: plain H input, 2: dec L0 (x_tgt ++ pv from s_pvl)
template <int KIND, int KI>
__device__ void gru_tile(const float* __restrict__ actA, const float* __restrict__ actB, int t,
                         const float* __restrict__ wi, const float* __restrict__ wh,
                         const float* __restrict__ bi, const float* __restrict__ bh,
                         const float* __restrict__ hprev, float* __restrict__ hout,
                         int b0, int g, float* __restrict__ s_act, float* __restrict__ s_w,
                         const float* __restrict__ s_pvl) {
  const int tid = threadIdx.x;
  const int bl = tid & 31;
  const int hc = tid >> 5;            // 0..15
  const int hid = (g << 4) + hc;
  const int row = tid >> 4, ko = (tid & 15) << 2;
  float aR = 0.f, aZ = 0.f, aI = 0.f, aN = 0.f;

  constexpr int NTI = (KI + 63) >> 6;
  constexpr int NTT = NTI + 8;

  float4 wv0 = {0,0,0,0}, wv1 = {0,0,0,0}, av = {0,0,0,0};
  int n4 = 0; bool a_valid = false;
  load_tile_regs<KIND, KI>(0, tid, b0, g, t, row, ko, actA, actB, wi, wh, hprev,
                           wv0, wv1, av, n4, a_valid);

  for (int kt = 0; kt < NTT; ++kt) {
    const bool is_input = (kt < NTI);
    const int k0i = kt << 6;
    const int cnt = is_input ? ((KI - k0i >= 64) ? 64 : (KI - k0i)) : 64;

    __syncthreads();   // previous tile's compute done reading LDS
    // regs -> LDS
    {
      float4* d4 = (float4*)s_w;
      if (tid < n4) d4[tid] = wv0;
      if (tid + 512 < n4) d4[tid + 512] = wv1;
      if (a_valid) {
        s_act[(ko + 0) * 33 + row] = av.x; s_act[(ko + 1) * 33 + row] = av.y;
        s_act[(ko + 2) * 33 + row] = av.z; s_act[(ko + 3) * 33 + row] = av.w;
      }
      if (KIND == 2 && is_input && k0i >= 128) {
        if ((tid & 15) == 0) {
#pragma unroll
          for (int i2 = 0; i2 < 5; ++i2) s_act[i2 * 33 + row] = s_pvl[(row << 3) + i2];
        }
      }
    }
    __syncthreads();
    // prefetch next tile into regs (latency hides under compute below)
    if (kt + 1 < NTT)
      load_tile_regs<KIND, KI>(kt + 1, tid, b0, g, t, row, ko, actA, actB, wi, wh, hprev,
                               wv0, wv1, av, n4, a_valid);
    // compute
    if (is_input) {
      if (cnt == 64) {
#pragma unroll 16
        for (int k = 0; k < 64; ++k) GRU_FMA(aI)
      } else {
        for (int k = 0; k < cnt; ++k) GRU_FMA(aI)
      }
    } else {
#pragma unroll 16
      for (int k = 0; k < 64; ++k) GRU_FMA(aN)
    }
  }

  // epilogue (PyTorch GRU: r,z,n gate order)
  float r = sigm(aR + bi[hid] + bh[hid]);
  float z = sigm(aZ + bi[512 + hid] + bh[512 + hid]);
  float n = tanhx(aI + bi[1024 + hid] + r * (aN + bh[1024 + hid]));
  float hp = hprev[(size_t)(b0 + bl) * H_ + hid];
  hout[(size_t)(b0 + bl) * H_ + hid] = (1.f - z) * n + z * hp;
}

// ---------------- the persistent kernel ----------------
__global__ __launch_bounds__(NTHR) void k_main(
    float* __restrict__ ws, const float* __restrict__ x_cv, const float* __restrict__ x_tgt,
    const float* __restrict__ e_bi0, const float* __restrict__ e_bh0,
    const float* __restrict__ e_bi1, const float* __restrict__ e_bh1,
    const float* __restrict__ d_bi0, const float* __restrict__ d_bh0,
    const float* __restrict__ d_bi1, const float* __restrict__ d_bh1,
    const float* __restrict__ fc1_b, const float* __restrict__ fc2_W, const float* __restrict__ fc2_b,
    const float* __restrict__ he1_b, const float* __restrict__ he2_W, const float* __restrict__ he2_b,
    float* __restrict__ out) {
  __shared__ float s_act[64 * 33];
  __shared__ float s_w[64 * 48];
  __shared__ float s_pv[256];        // [32 rows][8] pv values for this b-group
  __shared__ float s_sb[32 * 132];   // staging for s1/s2 rows

  const int tid = threadIdx.x;
  const int wg = blockIdx.x;
  // XCD-local weight sharing: the 8 WGs sharing hidden-group ji are wg = ji + 32*bi,
  // all congruent mod 8 -> same XCD under round-robin dispatch.
  const int ji = wg & 31;            // 0..31 hidden group
  const int bi = wg >> 5;            // 0..7 batch group
  const int b0 = bi << 5;            // 32 rows per group

  unsigned* bar = (unsigned*)ws;
  float* xemb = ws + OF_XEMB;
  float* hA[2] = {ws + OF_HA, ws + OF_HA + 131072};
  float* hB[2] = {ws + OF_HB, ws + OF_HB + 131072};
  float* pvst = ws + OF_PV;
  float* s1g = ws + OF_S1;
  float* s2g = ws + OF_S2;
  const float* wE0I = ws + OF_E0I; const float* wE0H = ws + OF_E0H;
  const float* wE1I = ws + OF_E1I; const float* wE1H = ws + OF_E1H;
  const float* wD0I = ws + OF_D0I; const float* wD0H = ws + OF_D0H;
  const float* wD1I = ws + OF_D1I; const float* wD1H = ws + OF_D1H;
  const float* wFH  = ws + OF_FH;

  // ======== encoder: L0 and L1 pipelined (L1 lags one step) ========
  for (int s = 0; s <= TE_; ++s) {
    if (s < TE_)
      gru_tile<0, KE0_>(x_cv, xemb, s, wE0I, wE0H, e_bi0, e_bh0,
                        hA[(s + 1) & 1], hA[s & 1], b0, ji, s_act, s_w, nullptr);
    if (s >= 1)
      gru_tile<1, 512>(hA[(s + 1) & 1], nullptr, 0, wE1I, wE1H, e_bi1, e_bh1,
                       hB[s & 1], hB[(s + 1) & 1], b0, ji, s_act, s_w, nullptr);
    bar_sync(bar, wg);
  }
  // h1_fin in hA[1], h2_fin in hB[1]

  // ======== decoder ========
  for (int t = 0; t <= T_; ++t) {
    // ---- heads of step t-1 (pv feedback + outputs), or pv_init at t==0 ----
    if (t == 0) {
      if (tid < 256) s_pv[tid] = pvst[(b0 << 3) + tid];
      __syncthreads();
    } else {
      { // stage s1 rows for this b-group
        int row = tid >> 4, co = (tid & 15) << 3;
        float4 v0 = *(const float4*)(s1g + (size_t)(b0 + row) * 128 + co);
        float4 v1 = *(const float4*)(s1g + (size_t)(b0 + row) * 128 + co + 4);
        *(float4*)(s_sb + row * 132 + co) = v0;
        *(float4*)(s_sb + row * 132 + co + 4) = v1;
      }
      __syncthreads();
      if (tid < 160) { // pv = s1 @ fc2^T + b  (redundant per WG; needed for pv feedback)
        int bl2 = tid & 31, p = tid >> 5;
        float acc = fc2_b[p];
#pragma unroll 8
        for (int c = 0; c < 128; ++c) acc = fmaf(s_sb[bl2 * 132 + c], fc2_W[p * 128 + c], acc);
        s_pv[(bl2 << 3) + p] = acc;
      }
      __syncthreads();
      if (ji == 1 && tid < 160) { // one WG per b-group writes pv output
        int bl2 = tid & 31, p = tid >> 5;
        out[((size_t)(b0 + bl2) * T_ + (t - 1)) * 5 + p] = s_pv[(bl2 << 3) + p];
      }
      if (ji == 0) { // one WG per b-group computes + writes he output
        int row = tid >> 4, co = (tid & 15) << 3;
        float4 v0 = *(const float4*)(s2g + (size_t)(b0 + row) * 128 + co);
        float4 v1 = *(const float4*)(s2g + (size_t)(b0 + row) * 128 + co + 4);
        *(float4*)(s_sb + row * 132 + co) = v0;
        *(float4*)(s_sb + row * 132 + co + 4) = v1;
        __syncthreads();
        int bl2 = tid & 31, e = tid >> 5;
        float acc = he2_b[e];
#pragma unroll 8
        for (int c = 0; c < 128; ++c) acc = fmaf(s_sb[bl2 * 132 + c], he2_W[e * 128 + c], acc);
        out[OUT_HE_OFS + ((size_t)(b0 + bl2) * T_ + (t - 1)) * 16 + e] = acc;
      }
    }

    if (t < T_) {
      // ---- phase D0: d1_t ----
      gru_tile<2, KD0_>(x_tgt, nullptr, t, wD0I, wD0H, d_bi0, d_bh0,
                        hA[(t + 1) & 1], hA[t & 1], b0, ji, s_act, s_w, s_pv);
      bar_sync(bar, wg);
      // ---- phase D1: d2_t ----
      gru_tile<1, 512>(hA[t & 1], nullptr, 0, wD1I, wD1H, d_bi1, d_bh1,
                       hB[(t + 1) & 1], hB[t & 1], b0, ji, s_act, s_w, nullptr);
      bar_sync(bar, wg);
      // ---- phase H1: s1 = relu(d2@fc1^T + b), s2 = relu(d2@he1^T + b) ----
      {
        const float* d2 = hB[t & 1];
        const int bl2 = tid & 31, c = tid >> 5; // c 0..15, active c<8
        const int row = tid >> 4, ko = (tid & 15) << 2;
        float acc = 0.f;
        float4 wv = {0,0,0,0}, av;
        if (tid < 128) wv = ((const float4*)(wFH + ((size_t)(ji << 9)) * 8))[tid];
        av = *(const float4*)(d2 + (size_t)(b0 + row) * H_ + ko);
        for (int kt = 0; kt < 8; ++kt) {
          __syncthreads();
          if (tid < 128) ((float4*)s_w)[tid] = wv;
          s_act[(ko + 0) * 33 + row] = av.x; s_act[(ko + 1) * 33 + row] = av.y;
          s_act[(ko + 2) * 33 + row] = av.z; s_act[(ko + 3) * 33 + row] = av.w;
          __syncthreads();
          if (kt + 1 < 8) {
            int k0 = (kt + 1) << 6;
            if (tid < 128) wv = ((const float4*)(wFH + ((size_t)(ji << 9) + k0) * 8))[tid];
            av = *(const float4*)(d2 + (size_t)(b0 + row) * H_ + k0 + ko);
          }
          if (c < 8) {
#pragma unroll 16
            for (int k = 0; k < 64; ++k) acc = fmaf(s_act[k * 33 + bl2], s_w[(k << 3) + c], acc);
          }
        }
        if (c < 4)
          s1g[(size_t)(b0 + bl2) * 128 + (ji << 2) + c] = fmaxf(acc + fc1_b[(ji << 2) + c], 0.f);
        else if (c < 8)
          s2g[(size_t)(b0 + bl2) * 128 + (ji << 2) + c - 4] = fmaxf(acc + he1_b[(ji << 2) + c - 4], 0.f);
      }
      bar_sync(bar, wg);
    }
  }
}

// ---------------- host ----------------
extern "C" void kernel_launch(void* const* d_in, const int* in_sizes, int n_in,
                              void* d_out, int out_size, void* d_ws, size_t ws_size,
                              hipStream_t stream) {
  float* ws = (float*)d_ws;
  const float* x_cv   = (const float*)d_in[0];
  const float* x_tgt  = (const float*)d_in[1];
  const float* pv_init= (const float*)d_in[2];
  const int*   scen   = (const int*)d_in[3];
  const float* emb    = (const float*)d_in[4];
  const float* eWih0  = (const float*)d_in[5];
  const float* eWhh0  = (const float*)d_in[6];
  const float* ebi0   = (const float*)d_in[7];
  const float* ebh0   = (const float*)d_in[8];
  const float* eWih1  = (const float*)d_in[9];
  const float* eWhh1  = (const float*)d_in[10];
  const float* ebi1   = (const float*)d_in[11];
  const float* ebh1   = (const float*)d_in[12];
  const float* dWih0  = (const float*)d_in[13];
  const float* dWhh0  = (const float*)d_in[14];
  const float* dbi0   = (const float*)d_in[15];
  const float* dbh0   = (const float*)d_in[16];
  const float* dWih1  = (const float*)d_in[17];
  const float* dWhh1  = (const float*)d_in[18];
  const float* dbi1   = (const float*)d_in[19];
  const float* dbh1   = (const float*)d_in[20];
  const float* fc1W   = (const float*)d_in[21];
  const float* fc1b   = (const float*)d_in[22];
  const float* fc2W   = (const float*)d_in[23];
  const float* fc2b   = (const float*)d_in[24];
  const float* he1W   = (const float*)d_in[25];
  const float* he1b   = (const float*)d_in[26];
  const float* he2W   = (const float*)d_in[27];
  const float* he2b   = (const float*)d_in[28];

  hipLaunchKernelGGL(k_init, dim3(512), dim3(256), 0, stream, ws, pv_init, scen, emb);
  hipLaunchKernelGGL(k_rearr, dim3(512), dim3(256), 0, stream, ws + OF_E0I, eWih0, 160);
  hipLaunchKernelGGL(k_rearr, dim3(512), dim3(256), 0, stream, ws + OF_E0H, eWhh0, 512);
  hipLaunchKernelGGL(k_rearr, dim3(512), dim3(256), 0, stream, ws + OF_E1I, eWih1, 512);
  hipLaunchKernelGGL(k_rearr, dim3(512), dim3(256), 0, stream, ws + OF_E1H, eWhh1, 512);
  hipLaunchKernelGGL(k_rearr, dim3(512), dim3(256), 0, stream, ws + OF_D0I, dWih0, 133);
  hipLaunchKernelGGL(k_rearr, dim3(512), dim3(256), 0, stream, ws + OF_D0H, dWhh0, 512);
  hipLaunchKernelGGL(k_rearr, dim3(512), dim3(256), 0, stream, ws + OF_D1I, dWih1, 512);
  hipLaunchKernelGGL(k_rearr, dim3(512), dim3(256), 0, stream, ws + OF_D1H, dWhh1, 512);
  hipLaunchKernelGGL(k_rearr_fh, dim3(256), dim3(256), 0, stream, ws + OF_FH, fc1W, he1W);

  hipLaunchKernelGGL(k_main, dim3(NBLK), dim3(NTHR), 0, stream,
                     ws, x_cv, x_tgt, ebi0, ebh0, ebi1, ebh1, dbi0, dbh0, dbi1, dbh1,
                     fc1b, fc2W, fc2b, he1b, he2W, he2b, (float*)d_out);
}